// Round 1
// baseline (47.613 us; speedup 1.0000x reference)
//
#include <hip/hip_runtime.h>

#define IN_F 4096
#define OUT_F 11008
#define GROUPSIZE 128
#define NGROUPS 32        // IN_F / GROUPSIZE
#define QROWS 512         // IN_F / 8 packed int32 rows
#define ZCOLS 1376        // OUT_F / 8 packed zero cols

// Block: 256 threads = 64 columns x 4 K-partitions.
// Each thread: one output column, 1/4 of K (1024 K values = 8 groups = 128 packed ints).
__global__ __launch_bounds__(256) void gptq_gemv_kernel(
    const float* __restrict__ x,       // [4, IN_F]
    const float* __restrict__ scales,  // [NGROUPS, OUT_F]
    const float* __restrict__ bias,    // [OUT_F]
    const int*   __restrict__ qweight, // [QROWS, OUT_F]
    const int*   __restrict__ qzeros,  // [NGROUPS, ZCOLS]
    float*       __restrict__ out)     // [4, OUT_F]
{
    __shared__ float part[4][4][64];   // [kpart][token][col]

    const int tid = threadIdx.x;
    const int col = tid & 63;
    const int kp  = tid >> 6;          // 0..3, wave-uniform (64 lanes/wave)
    const int n   = blockIdx.x * 64 + col;

    const unsigned zshift = 4u * (unsigned)(n & 7);
    const int      zcol   = n >> 3;

    float acc[4] = {0.f, 0.f, 0.f, 0.f};

    const int g0 = kp * (NGROUPS / 4);     // 8 groups per K-partition

    for (int g = g0; g < g0 + NGROUPS / 4; ++g) {
        const unsigned qz = (unsigned)qzeros[g * ZCOLS + zcol];
        const float zf = (float)(((qz >> zshift) & 0xFu) + 1u);
        const float sc = scales[g * OUT_F + n];

        float ga[4] = {0.f, 0.f, 0.f, 0.f};
        const int kkbase = g * (GROUPSIZE / 8);   // 16 packed ints per group

        #pragma unroll 4
        for (int t = 0; t < GROUPSIZE / 8; ++t) {
            const int kk = kkbase + t;
            const unsigned w = (unsigned)qweight[kk * OUT_F + n];
            // nibble unpack via byte masks -> v_cvt_f32_ubyteN
            const unsigned lo = w & 0x0F0F0F0Fu;         // nibbles j=0,2,4,6
            const unsigned hi = (w >> 4) & 0x0F0F0F0Fu;  // nibbles j=1,3,5,7
            float q[8];
            q[0] = (float)(lo & 0xFFu);
            q[1] = (float)(hi & 0xFFu);
            q[2] = (float)((lo >> 8) & 0xFFu);
            q[3] = (float)((hi >> 8) & 0xFFu);
            q[4] = (float)((lo >> 16) & 0xFFu);
            q[5] = (float)((hi >> 16) & 0xFFu);
            q[6] = (float)((lo >> 24) & 0xFFu);
            q[7] = (float)((hi >> 24) & 0xFFu);

            const int k0 = kk * 8;
            float xv[4][8];
            #pragma unroll
            for (int m = 0; m < 4; ++m) {
                const float4 a = *(const float4*)(x + m * IN_F + k0);
                const float4 b = *(const float4*)(x + m * IN_F + k0 + 4);
                xv[m][0] = a.x; xv[m][1] = a.y; xv[m][2] = a.z; xv[m][3] = a.w;
                xv[m][4] = b.x; xv[m][5] = b.y; xv[m][6] = b.z; xv[m][7] = b.w;
            }
            #pragma unroll
            for (int j = 0; j < 8; ++j) {
                const float d = q[j] - zf;
                #pragma unroll
                for (int m = 0; m < 4; ++m) ga[m] += xv[m][j] * d;
            }
        }
        #pragma unroll
        for (int m = 0; m < 4; ++m) acc[m] += sc * ga[m];
    }

    #pragma unroll
    for (int m = 0; m < 4; ++m) part[kp][m][col] = acc[m];
    __syncthreads();

    // Reduce the 4 K-partitions: thread t handles (token = t>>6, col = t&63).
    const int m = tid >> 6;
    const int c = tid & 63;
    const int nn = blockIdx.x * 64 + c;
    const float s = part[0][m][c] + part[1][m][c] + part[2][m][c] + part[3][m][c];
    out[m * OUT_F + nn] = s + bias[nn];
}

extern "C" void kernel_launch(void* const* d_in, const int* in_sizes, int n_in,
                              void* d_out, int out_size, void* d_ws, size_t ws_size,
                              hipStream_t stream) {
    const float* x       = (const float*)d_in[0];
    const float* scales  = (const float*)d_in[1];
    const float* bias    = (const float*)d_in[2];
    const int*   qweight = (const int*)d_in[3];
    const int*   qzeros  = (const int*)d_in[4];
    float*       out     = (float*)d_out;

    dim3 grid(OUT_F / 64);   // 172 blocks
    gptq_gemv_kernel<<<grid, 256, 0, stream>>>(x, scales, bias, qweight, qzeros, out);
}

// Round 2
// 16.837 us; speedup vs baseline: 2.8279x; 2.8279x over previous
//
#include <hip/hip_runtime.h>

#define IN_F 4096
#define OUT_F 11008
#define GROUPSIZE 128
#define NGROUPS 32        // IN_F / GROUPSIZE
#define QROWS 512         // IN_F / 8 packed int32 rows
#define ZCOLS 1376        // OUT_F / 8 packed zero cols
#define KSPLIT 8          // grid-level K split (NGROUPS / 4 in-block parts)
#define WS_FLOATS (KSPLIT * 4 * OUT_F)   // partials: [KSPLIT][4][OUT_F]

// ---------------- Stage 1: partial GEMV, one group per thread ----------------
// Block: 256 threads = 64 columns x 4 k-parts. Grid: (OUT_F/64, KSPLIT).
// Global group index g = blockIdx.y*4 + (tid>>6)  -> each thread does exactly
// one GPTQ group (128 K values = 16 packed int32s) for one output column.
__global__ __launch_bounds__(256) void gptq_partial_kernel(
    const float* __restrict__ x,       // [4, IN_F]
    const float* __restrict__ scales,  // [NGROUPS, OUT_F]
    const int*   __restrict__ qweight, // [QROWS, OUT_F]
    const int*   __restrict__ qzeros,  // [NGROUPS, ZCOLS]
    float*       __restrict__ ws)      // [KSPLIT, 4, OUT_F]
{
    __shared__ float part[4][4][64];   // [kpart][token][col]

    const int tid = threadIdx.x;
    const int col = tid & 63;
    const int kp  = tid >> 6;                        // 0..3, wave-uniform
    const int n   = blockIdx.x * 64 + col;
    const int g   = blockIdx.y * 4 + kp;             // group 0..31
    // tell the compiler the group index is wave-uniform -> scalar x loads
    const int gu  = __builtin_amdgcn_readfirstlane(g);

    const unsigned qz = (unsigned)qzeros[g * ZCOLS + (n >> 3)];
    const float zf = (float)(((qz >> (4u * (unsigned)(n & 7))) & 0xFu) + 1u);
    const float sc = scales[g * OUT_F + n];

    float ga[4] = {0.f, 0.f, 0.f, 0.f};
    const int kkbase = gu * (GROUPSIZE / 8);         // 16 packed ints per group

    #pragma unroll
    for (int t = 0; t < GROUPSIZE / 8; ++t) {
        const int kk = kkbase + t;
        const unsigned w = (unsigned)qweight[kk * OUT_F + n];
        const unsigned lo = w & 0x0F0F0F0Fu;         // nibbles j=0,2,4,6
        const unsigned hi = (w >> 4) & 0x0F0F0F0Fu;  // nibbles j=1,3,5,7
        float q[8];
        q[0] = (float)(lo & 0xFFu);
        q[1] = (float)(hi & 0xFFu);
        q[2] = (float)((lo >> 8) & 0xFFu);
        q[3] = (float)((hi >> 8) & 0xFFu);
        q[4] = (float)((lo >> 16) & 0xFFu);
        q[5] = (float)((hi >> 16) & 0xFFu);
        q[6] = (float)((lo >> 24) & 0xFFu);
        q[7] = (float)((hi >> 24) & 0xFFu);

        const int k0 = kk * 8;                       // wave-uniform
        #pragma unroll
        for (int j = 0; j < 8; ++j) {
            const float d = q[j] - zf;
            #pragma unroll
            for (int m = 0; m < 4; ++m) ga[m] += x[m * IN_F + k0 + j] * d;
        }
    }

    #pragma unroll
    for (int m = 0; m < 4; ++m) part[kp][m][col] = sc * ga[m];
    __syncthreads();

    // Reduce the 4 in-block k-parts: thread t -> (token = t>>6, col = t&63).
    const int m = tid >> 6;
    const int c = tid & 63;
    const int nn = blockIdx.x * 64 + c;
    const float s = part[0][m][c] + part[1][m][c] + part[2][m][c] + part[3][m][c];
    ws[(blockIdx.y * 4 + m) * OUT_F + nn] = s;
}

// ---------------- Stage 2: reduce KSPLIT partials + bias ----------------
// Grid: (OUT_F/256, 4). Each thread: one (token, col) output.
__global__ __launch_bounds__(256) void gptq_reduce_kernel(
    const float* __restrict__ ws,      // [KSPLIT, 4, OUT_F]
    const float* __restrict__ bias,    // [OUT_F]
    float*       __restrict__ out)     // [4, OUT_F]
{
    const int n = blockIdx.x * 256 + threadIdx.x;    // 0..OUT_F-1 (11008 = 43*256)
    const int m = blockIdx.y;                        // token
    float s = bias[n];
    #pragma unroll
    for (int ks = 0; ks < KSPLIT; ++ks)
        s += ws[(ks * 4 + m) * OUT_F + n];
    out[m * OUT_F + n] = s;
}

// ---------------- Fallback: single-kernel version (if ws too small) ----------
__global__ __launch_bounds__(256) void gptq_gemv_fused(
    const float* __restrict__ x, const float* __restrict__ scales,
    const float* __restrict__ bias, const int* __restrict__ qweight,
    const int* __restrict__ qzeros, float* __restrict__ out)
{
    __shared__ float part[4][4][64];
    const int tid = threadIdx.x;
    const int col = tid & 63;
    const int kp  = tid >> 6;
    const int n   = blockIdx.x * 64 + col;
    const unsigned zshift = 4u * (unsigned)(n & 7);
    const int zcol = n >> 3;
    float acc[4] = {0.f, 0.f, 0.f, 0.f};
    const int g0 = kp * (NGROUPS / 4);
    for (int g = g0; g < g0 + NGROUPS / 4; ++g) {
        const unsigned qz = (unsigned)qzeros[g * ZCOLS + zcol];
        const float zf = (float)(((qz >> zshift) & 0xFu) + 1u);
        const float sc = scales[g * OUT_F + n];
        float ga[4] = {0.f, 0.f, 0.f, 0.f};
        const int kkbase = g * (GROUPSIZE / 8);
        #pragma unroll 4
        for (int t = 0; t < GROUPSIZE / 8; ++t) {
            const int kk = kkbase + t;
            const unsigned w = (unsigned)qweight[kk * OUT_F + n];
            const unsigned lo = w & 0x0F0F0F0Fu;
            const unsigned hi = (w >> 4) & 0x0F0F0F0Fu;
            float q[8];
            q[0] = (float)(lo & 0xFFu);         q[1] = (float)(hi & 0xFFu);
            q[2] = (float)((lo >> 8) & 0xFFu);  q[3] = (float)((hi >> 8) & 0xFFu);
            q[4] = (float)((lo >> 16) & 0xFFu); q[5] = (float)((hi >> 16) & 0xFFu);
            q[6] = (float)((lo >> 24) & 0xFFu); q[7] = (float)((hi >> 24) & 0xFFu);
            const int k0 = kk * 8;
            #pragma unroll
            for (int j = 0; j < 8; ++j) {
                const float d = q[j] - zf;
                #pragma unroll
                for (int m = 0; m < 4; ++m) acc[m] += x[m * IN_F + k0 + j] * d * sc;
            }
        }
        (void)0;
    }
    #pragma unroll
    for (int m = 0; m < 4; ++m) part[kp][m][col] = acc[m];
    __syncthreads();
    const int m = tid >> 6;
    const int c = tid & 63;
    const int nn = blockIdx.x * 64 + c;
    const float s = part[0][m][c] + part[1][m][c] + part[2][m][c] + part[3][m][c];
    out[m * OUT_F + nn] = s + bias[nn];
}

extern "C" void kernel_launch(void* const* d_in, const int* in_sizes, int n_in,
                              void* d_out, int out_size, void* d_ws, size_t ws_size,
                              hipStream_t stream) {
    const float* x       = (const float*)d_in[0];
    const float* scales  = (const float*)d_in[1];
    const float* bias    = (const float*)d_in[2];
    const int*   qweight = (const int*)d_in[3];
    const int*   qzeros  = (const int*)d_in[4];
    float*       out     = (float*)d_out;

    if (ws_size >= WS_FLOATS * sizeof(float)) {
        float* ws = (float*)d_ws;
        dim3 g1(OUT_F / 64, KSPLIT);   // (172, 8) = 1376 blocks
        gptq_partial_kernel<<<g1, 256, 0, stream>>>(x, scales, qweight, qzeros, ws);
        dim3 g2(OUT_F / 256, 4);       // (43, 4)
        gptq_reduce_kernel<<<g2, 256, 0, stream>>>(ws, bias, out);
    } else {
        dim3 grid(OUT_F / 64);
        gptq_gemv_fused<<<grid, 256, 0, stream>>>(x, scales, bias, qweight, qzeros, out);
    }
}